// Round 1
// baseline (14513.512 us; speedup 1.0000x reference)
//
#include <hip/hip_runtime.h>
#include <hip/hip_bf16.h>
#include <math.h>

#define N_NODES 100000
#define N_EDGES 1000000
#define F_IN    128
#define ED_DIM  16
#define H_HEADS 5
#define C_CH    16
#define HC      80
#define NEG_SLOPE 0.2f

// ---------- float atomic max via ordered-int trick ----------
// init bits must be 0xFF7FFFFF (-FLT_MAX). Works for mixed signs:
// non-negative floats compare as ints (atomicMax int), negative floats
// compare inverted as unsigned (atomicMin uint). Stored bits are always the
// raw float bits of the current max.
__device__ __forceinline__ void atomicMaxFloatBits(int* addr, float val) {
    int iv = __float_as_int(val);
    if (iv >= 0) {
        atomicMax(addr, iv);
    } else {
        atomicMin((unsigned int*)addr, (unsigned int)iv);
    }
}

// ---------- node transform: out[n,j] = sum_d A[n,d]*W[j,d] + bias[j] ----------
// tile: 64 nodes x 80 outputs per block, 320 threads, 4x4 micro-tile
template<int DIN>
__global__ __launch_bounds__(320) void k_xform(
    const float* __restrict__ A, const float* __restrict__ W,
    const float* __restrict__ bias, float* __restrict__ out, int nn) {
    __shared__ float As[16][68];  // [k][node], padded row (68*4=272B, 16B aligned)
    __shared__ float Ws[16][80];  // [k][j]
    const int t  = threadIdx.x;
    const int n0 = blockIdx.x * 64;
    const int tn = (t & 15) * 4;   // node offset in tile
    const int tj = (t >> 4) * 4;   // j offset (0..76)
    float4 acc[4];
    acc[0] = make_float4(0.f,0.f,0.f,0.f);
    acc[1] = acc[0]; acc[2] = acc[0]; acc[3] = acc[0];

    for (int k0 = 0; k0 < DIN; k0 += 16) {
        __syncthreads();
        for (int i = t; i < 64*16; i += 320) {
            int nl = i >> 4, kk = i & 15;
            int n = n0 + nl;
            As[kk][nl] = (n < nn) ? A[(size_t)n*DIN + k0 + kk] : 0.f;
        }
        for (int i = t; i < 80*16; i += 320) {
            int jj = i >> 4, kk = i & 15;
            Ws[kk][jj] = W[(size_t)jj*DIN + k0 + kk];
        }
        __syncthreads();
        #pragma unroll
        for (int k = 0; k < 16; ++k) {
            const float4 av = *(const float4*)&As[k][tn];
            const float4 wv = *(const float4*)&Ws[k][tj];
            acc[0].x += av.x*wv.x; acc[0].y += av.x*wv.y; acc[0].z += av.x*wv.z; acc[0].w += av.x*wv.w;
            acc[1].x += av.y*wv.x; acc[1].y += av.y*wv.y; acc[1].z += av.y*wv.z; acc[1].w += av.y*wv.w;
            acc[2].x += av.z*wv.x; acc[2].y += av.z*wv.y; acc[2].z += av.z*wv.z; acc[2].w += av.z*wv.w;
            acc[3].x += av.w*wv.x; acc[3].y += av.w*wv.y; acc[3].z += av.w*wv.z; acc[3].w += av.w*wv.w;
        }
    }
    const float4 bv = *(const float4*)(bias + tj);
    #pragma unroll
    for (int u = 0; u < 4; ++u) {
        int n = n0 + tn + u;
        if (n < nn) {
            float4 o;
            o.x = acc[u].x + bv.x; o.y = acc[u].y + bv.y;
            o.z = acc[u].z + bv.z; o.w = acc[u].w + bv.w;
            *(float4*)(out + (size_t)n*HC + tj) = o;
        }
    }
}

// ---------- per-(edge,head) alpha + segment max ----------
// block 320: wave w handles head h=w (uniform per wave), 64 edges per block
__global__ __launch_bounds__(320) void k_edge_alpha(
    const float* __restrict__ xl, const float* __restrict__ xr,
    const float* __restrict__ eattr, const float* __restrict__ we,
    const float* __restrict__ att, const int* __restrict__ src,
    const int* __restrict__ dst, float* __restrict__ alpha,
    int* __restrict__ amax) {
    __shared__ float weS[HC*ED_DIM];  // 1280 floats
    __shared__ float attS[HC];
    const int t = threadIdx.x;
    for (int i = t; i < HC*ED_DIM; i += 320) weS[i] = we[i];
    if (t < HC) attS[t] = att[t];
    __syncthreads();
    const int h = t >> 6;                      // wave-uniform
    const int e = blockIdx.x * 64 + (t & 63);  // E divisible by 64
    const int s = src[e];
    const int d = dst[e];
    const float4* ea4 = (const float4*)(eattr + (size_t)e * ED_DIM);
    const float4 ea0 = ea4[0], ea1 = ea4[1], ea2 = ea4[2], ea3 = ea4[3];
    const float4* xl4 = (const float4*)(xl + (size_t)s*HC + h*C_CH);
    const float4* xr4 = (const float4*)(xr + (size_t)d*HC + h*C_CH);
    const float4* weH = (const float4*)(weS + h*C_CH*ED_DIM);  // broadcast reads
    const float4* at4 = (const float4*)(attS + h*C_CH);
    float acc = 0.f;
    #pragma unroll
    for (int cg = 0; cg < 4; ++cg) {
        const float4 xlv = xl4[cg];
        const float4 xrv = xr4[cg];
        const float4 at  = at4[cg];
        float emv[4];
        #pragma unroll
        for (int u = 0; u < 4; ++u) {
            const int c = cg*4 + u;
            const float4 w0 = weH[c*4+0], w1 = weH[c*4+1], w2 = weH[c*4+2], w3 = weH[c*4+3];
            emv[u] = ea0.x*w0.x + ea0.y*w0.y + ea0.z*w0.z + ea0.w*w0.w
                   + ea1.x*w1.x + ea1.y*w1.y + ea1.z*w1.z + ea1.w*w1.w
                   + ea2.x*w2.x + ea2.y*w2.y + ea2.z*w2.z + ea2.w*w2.w
                   + ea3.x*w3.x + ea3.y*w3.y + ea3.z*w3.z + ea3.w*w3.w;
        }
        float4 m;
        m.x = xlv.x + xrv.x + emv[0];
        m.y = xlv.y + xrv.y + emv[1];
        m.z = xlv.z + xrv.z + emv[2];
        m.w = xlv.w + xrv.w + emv[3];
        m.x = fmaxf(m.x, 0.f) + NEG_SLOPE*fminf(m.x, 0.f);
        m.y = fmaxf(m.y, 0.f) + NEG_SLOPE*fminf(m.y, 0.f);
        m.z = fmaxf(m.z, 0.f) + NEG_SLOPE*fminf(m.z, 0.f);
        m.w = fmaxf(m.w, 0.f) + NEG_SLOPE*fminf(m.w, 0.f);
        acc += m.x*at.x + m.y*at.y + m.z*at.z + m.w*at.w;
    }
    alpha[(size_t)h*N_EDGES + e] = acc;
    atomicMaxFloatBits(amax + (size_t)h*N_NODES + d, acc);
}

// ---------- exp + segment sum ----------
__global__ __launch_bounds__(320) void k_edge_exp(
    float* __restrict__ alpha, const int* __restrict__ amax,
    float* __restrict__ den, const int* __restrict__ dst) {
    const int t = threadIdx.x;
    const int h = t >> 6;
    const int e = blockIdx.x * 64 + (t & 63);
    const int d = dst[e];
    const float al = alpha[(size_t)h*N_EDGES + e];
    const float mx = __int_as_float(amax[(size_t)h*N_NODES + d]);
    const float ex = __expf(al - mx);
    alpha[(size_t)h*N_EDGES + e] = ex;
    unsafeAtomicAdd(den + (size_t)h*N_NODES + d, ex);
}

// ---------- weighted scatter ----------
__global__ __launch_bounds__(320) void k_edge_scatter(
    const float* __restrict__ xl, const float* __restrict__ ex,
    const float* __restrict__ den, const int* __restrict__ src,
    const int* __restrict__ dst, float* __restrict__ out) {
    const int t = threadIdx.x;
    const int h = t >> 6;
    const int e = blockIdx.x * 64 + (t & 63);
    const int s = src[e];
    const int d = dst[e];
    float a = ex[(size_t)h*N_EDGES + e];
    const float dn = den[(size_t)h*N_NODES + d];
    a = a / (dn + 1e-16f);
    const float4* xl4 = (const float4*)(xl + (size_t)s*HC + h*C_CH);
    float* ob = out + (size_t)d*HC + h*C_CH;
    #pragma unroll
    for (int cg = 0; cg < 4; ++cg) {
        const float4 xv = xl4[cg];
        unsafeAtomicAdd(ob + cg*4 + 0, xv.x * a);
        unsafeAtomicAdd(ob + cg*4 + 1, xv.y * a);
        unsafeAtomicAdd(ob + cg*4 + 2, xv.z * a);
        unsafeAtomicAdd(ob + cg*4 + 3, xv.w * a);
    }
}

// ---------- init amax/den ----------
__global__ void k_init(int* __restrict__ amax, float* __restrict__ den, int n) {
    const int i = blockIdx.x * 256 + threadIdx.x;
    if (i < n) {
        amax[i] = (int)0xFF7FFFFFu;  // -FLT_MAX bits
        den[i]  = 0.f;
    }
}

// ---------- bias + optional relu ----------
__global__ void k_bias_act(float* __restrict__ out, const float* __restrict__ bias,
                           int n_total, int relu) {
    const int i = blockIdx.x * 256 + threadIdx.x;
    if (i < n_total) {
        float v = out[i] + bias[i % HC];
        if (relu) v = fmaxf(v, 0.f);
        out[i] = v;
    }
}

extern "C" void kernel_launch(void* const* d_in, const int* in_sizes, int n_in,
                              void* d_out, int out_size, void* d_ws, size_t ws_size,
                              hipStream_t stream) {
    (void)in_sizes; (void)n_in; (void)out_size; (void)ws_size;
    const float* x     = (const float*)d_in[0];
    const int*   ei    = (const int*)d_in[1];
    const float* eattr = (const float*)d_in[2];
    const int* srcp = ei;
    const int* dstp = ei + N_EDGES;

    // workspace layout (floats): h[N*80] xl[N*80] xr[N*80] alpha[E*5] amax[N*5] den[N*5]
    float* h     = (float*)d_ws;
    float* xl    = h  + (size_t)N_NODES*HC;
    float* xr    = xl + (size_t)N_NODES*HC;
    float* alpha = xr + (size_t)N_NODES*HC;
    int*   amax  = (int*)(alpha + (size_t)N_EDGES*H_HEADS);
    float* den   = (float*)(amax + (size_t)N_NODES*H_HEADS);
    float* outp  = (float*)d_out;

    const dim3 bx(320);
    const dim3 gx((N_NODES + 63) / 64);
    const dim3 ge(N_EDGES / 64);

    for (int L = 0; L < 3; ++L) {
        const float* in   = (L == 0) ? x : h;
        float*       oacc = (L == 2) ? outp : h;
        const float* wl   = (const float*)d_in[3 + L*7 + 0];
        const float* bl   = (const float*)d_in[3 + L*7 + 1];
        const float* wr   = (const float*)d_in[3 + L*7 + 2];
        const float* br   = (const float*)d_in[3 + L*7 + 3];
        const float* we   = (const float*)d_in[3 + L*7 + 4];
        const float* att  = (const float*)d_in[3 + L*7 + 5];
        const float* bias = (const float*)d_in[3 + L*7 + 6];

        if (L == 0) {
            k_xform<F_IN><<<gx, bx, 0, stream>>>(in, wl, bl, xl, N_NODES);
            k_xform<F_IN><<<gx, bx, 0, stream>>>(in, wr, br, xr, N_NODES);
        } else {
            k_xform<HC><<<gx, bx, 0, stream>>>(in, wl, bl, xl, N_NODES);
            k_xform<HC><<<gx, bx, 0, stream>>>(in, wr, br, xr, N_NODES);
        }
        // zero the output accumulator (input h no longer needed after xform)
        hipMemsetAsync(oacc, 0, (size_t)N_NODES*HC*sizeof(float), stream);
        k_init<<<(N_NODES*H_HEADS + 255)/256, 256, 0, stream>>>(amax, den, N_NODES*H_HEADS);
        k_edge_alpha<<<ge, bx, 0, stream>>>(xl, xr, eattr, we, att, srcp, dstp, alpha, amax);
        k_edge_exp<<<ge, bx, 0, stream>>>(alpha, amax, den, dstp);
        k_edge_scatter<<<ge, bx, 0, stream>>>(xl, alpha, den, srcp, dstp, oacc);
        k_bias_act<<<(N_NODES*HC + 255)/256, 256, 0, stream>>>(oacc, bias, N_NODES*HC, (L < 2) ? 1 : 0);
    }
}

// Round 2
// 1715.627 us; speedup vs baseline: 8.4596x; 8.4596x over previous
//
#include <hip/hip_runtime.h>
#include <hip/hip_bf16.h>
#include <math.h>

#define N_NODES 100000
#define N_EDGES 1000000
#define F_IN    128
#define ED_DIM  16
#define H_HEADS 5
#define C_CH    16
#define HC      80
#define NEG_SLOPE 0.2f

// ================= CSR build (graph is static across layers) =================

__global__ void k_hist(const int* __restrict__ dst, int* __restrict__ count) {
    const int e = blockIdx.x * 256 + threadIdx.x;
    if (e < N_EDGES) atomicAdd(count + dst[e], 1);
}

// single-block exclusive scan of count[N] -> rowstart[N+1]
__global__ __launch_bounds__(1024) void k_scan(const int* __restrict__ count,
                                               int* __restrict__ rowstart) {
    __shared__ int part[1024];
    const int t = threadIdx.x;
    const int CH = (N_NODES + 1023) / 1024;  // 98
    const int base = t * CH;
    int s = 0;
    for (int i = 0; i < CH; ++i) {
        int idx = base + i;
        if (idx < N_NODES) s += count[idx];
    }
    part[t] = s;
    __syncthreads();
    for (int off = 1; off < 1024; off <<= 1) {
        int v = (t >= off) ? part[t - off] : 0;
        __syncthreads();
        part[t] += v;
        __syncthreads();
    }
    int excl = (t == 0) ? 0 : part[t - 1];
    for (int i = 0; i < CH; ++i) {
        int idx = base + i;
        if (idx < N_NODES) { rowstart[idx] = excl; excl += count[idx]; }
    }
    if (t == 1023) rowstart[N_NODES] = part[1023];
}

__global__ void k_place(const int* __restrict__ src, const int* __restrict__ dst,
                        const int* __restrict__ rowstart, int* __restrict__ cursor,
                        int* __restrict__ perm, int* __restrict__ src_s,
                        int* __restrict__ dst_s) {
    const int e = blockIdx.x * 256 + threadIdx.x;
    if (e >= N_EDGES) return;
    const int d = dst[e];
    const int pos = rowstart[d] + atomicAdd(cursor + d, 1);
    perm[pos]  = e;
    src_s[pos] = src[e];
    dst_s[pos] = d;
}

// ============ node transform: out[n,j] = sum_d A[n,d]*W[j,d] + bias[j] =======
// tile: 64 nodes x 80 outputs per block, 320 threads, 4x4 micro-tile
template<int DIN>
__global__ __launch_bounds__(320) void k_xform(
    const float* __restrict__ A, const float* __restrict__ W,
    const float* __restrict__ bias, float* __restrict__ out, int nn) {
    __shared__ float As[16][68];
    __shared__ float Ws[16][80];
    const int t  = threadIdx.x;
    const int n0 = blockIdx.x * 64;
    const int tn = (t & 15) * 4;
    const int tj = (t >> 4) * 4;
    float4 acc[4];
    acc[0] = make_float4(0.f,0.f,0.f,0.f);
    acc[1] = acc[0]; acc[2] = acc[0]; acc[3] = acc[0];

    for (int k0 = 0; k0 < DIN; k0 += 16) {
        __syncthreads();
        for (int i = t; i < 64*16; i += 320) {
            int nl = i >> 4, kk = i & 15;
            int n = n0 + nl;
            As[kk][nl] = (n < nn) ? A[(size_t)n*DIN + k0 + kk] : 0.f;
        }
        for (int i = t; i < 80*16; i += 320) {
            int jj = i >> 4, kk = i & 15;
            Ws[kk][jj] = W[(size_t)jj*DIN + k0 + kk];
        }
        __syncthreads();
        #pragma unroll
        for (int k = 0; k < 16; ++k) {
            const float4 av = *(const float4*)&As[k][tn];
            const float4 wv = *(const float4*)&Ws[k][tj];
            acc[0].x += av.x*wv.x; acc[0].y += av.x*wv.y; acc[0].z += av.x*wv.z; acc[0].w += av.x*wv.w;
            acc[1].x += av.y*wv.x; acc[1].y += av.y*wv.y; acc[1].z += av.y*wv.z; acc[1].w += av.y*wv.w;
            acc[2].x += av.z*wv.x; acc[2].y += av.z*wv.y; acc[2].z += av.z*wv.z; acc[2].w += av.z*wv.w;
            acc[3].x += av.w*wv.x; acc[3].y += av.w*wv.y; acc[3].z += av.w*wv.z; acc[3].w += av.w*wv.w;
        }
    }
    const float4 bv = *(const float4*)(bias + tj);
    #pragma unroll
    for (int u = 0; u < 4; ++u) {
        int n = n0 + tn + u;
        if (n < nn) {
            float4 o;
            o.x = acc[u].x + bv.x; o.y = acc[u].y + bv.y;
            o.z = acc[u].z + bv.z; o.w = acc[u].w + bv.w;
            *(float4*)(out + (size_t)n*HC + tj) = o;
        }
    }
}

// ====== alpha logits in SORTED edge order (coalesced write, no atomics) ======
// block 320: wave w = head h (uniform), 64 sorted positions per block
__global__ __launch_bounds__(320) void k_alpha(
    const float* __restrict__ xl, const float* __restrict__ xr,
    const float* __restrict__ eattr, const float* __restrict__ we,
    const float* __restrict__ att, const int* __restrict__ perm,
    const int* __restrict__ src_s, const int* __restrict__ dst_s,
    float* __restrict__ alpha) {
    __shared__ float weS[HC*ED_DIM];
    __shared__ float attS[HC];
    const int t = threadIdx.x;
    for (int i = t; i < HC*ED_DIM; i += 320) weS[i] = we[i];
    if (t < HC) attS[t] = att[t];
    __syncthreads();
    const int h = t >> 6;                       // wave-uniform
    const int p = blockIdx.x * 64 + (t & 63);   // E divisible by 64
    const int e = perm[p];
    const int s = src_s[p];
    const int d = dst_s[p];
    const float4* ea4 = (const float4*)(eattr + (size_t)e * ED_DIM);
    const float4 ea0 = ea4[0], ea1 = ea4[1], ea2 = ea4[2], ea3 = ea4[3];
    const float4* xl4 = (const float4*)(xl + (size_t)s*HC + h*C_CH);
    const float4* xr4 = (const float4*)(xr + (size_t)d*HC + h*C_CH);
    const float4* weH = (const float4*)(weS + h*C_CH*ED_DIM);
    const float4* at4 = (const float4*)(attS + h*C_CH);
    float acc = 0.f;
    #pragma unroll
    for (int cg = 0; cg < 4; ++cg) {
        const float4 xlv = xl4[cg];
        const float4 xrv = xr4[cg];
        const float4 at  = at4[cg];
        float emv[4];
        #pragma unroll
        for (int u = 0; u < 4; ++u) {
            const int c = cg*4 + u;
            const float4 w0 = weH[c*4+0], w1 = weH[c*4+1], w2 = weH[c*4+2], w3 = weH[c*4+3];
            emv[u] = ea0.x*w0.x + ea0.y*w0.y + ea0.z*w0.z + ea0.w*w0.w
                   + ea1.x*w1.x + ea1.y*w1.y + ea1.z*w1.z + ea1.w*w1.w
                   + ea2.x*w2.x + ea2.y*w2.y + ea2.z*w2.z + ea2.w*w2.w
                   + ea3.x*w3.x + ea3.y*w3.y + ea3.z*w3.z + ea3.w*w3.w;
        }
        float4 m;
        m.x = xlv.x + xrv.x + emv[0];
        m.y = xlv.y + xrv.y + emv[1];
        m.z = xlv.z + xrv.z + emv[2];
        m.w = xlv.w + xrv.w + emv[3];
        m.x = fmaxf(m.x, 0.f) + NEG_SLOPE*fminf(m.x, 0.f);
        m.y = fmaxf(m.y, 0.f) + NEG_SLOPE*fminf(m.y, 0.f);
        m.z = fmaxf(m.z, 0.f) + NEG_SLOPE*fminf(m.z, 0.f);
        m.w = fmaxf(m.w, 0.f) + NEG_SLOPE*fminf(m.w, 0.f);
        acc += m.x*at.x + m.y*at.y + m.z*at.z + m.w*at.w;
    }
    alpha[(size_t)h*N_EDGES + p] = acc;   // coalesced
}

// ===== per-(node,head) softmax over CSR segment: exp in place + den ==========
__global__ void k_softmax(float* __restrict__ alpha, const int* __restrict__ rowstart,
                          float* __restrict__ den) {
    const int i = blockIdx.x * 256 + threadIdx.x;
    if (i >= N_NODES * H_HEADS) return;
    const int h = i / N_NODES;
    const int n = i - h * N_NODES;
    const int rs = rowstart[n], re = rowstart[n + 1];
    float* a = alpha + (size_t)h * N_EDGES;
    float mx = -3.402823466e38f;
    for (int p = rs; p < re; ++p) mx = fmaxf(mx, a[p]);
    float s = 0.f;
    for (int p = rs; p < re; ++p) {
        const float ex = __expf(a[p] - mx);
        a[p] = ex;
        s += ex;
    }
    den[(size_t)h * N_NODES + n] = s;
}

// ===== per-(node,channel) aggregation: out = sum(exp*xl[src])/den + bias =====
__global__ void k_aggregate(const float* __restrict__ xl, const float* __restrict__ expw,
                            const float* __restrict__ den, const int* __restrict__ src_s,
                            const int* __restrict__ rowstart, const float* __restrict__ bias,
                            float* __restrict__ out, int relu) {
    const int i = blockIdx.x * 256 + threadIdx.x;
    if (i >= N_NODES * HC) return;
    const int n  = i / HC;
    const int ch = i - n * HC;
    const int h  = ch >> 4;
    const int rs = rowstart[n], re = rowstart[n + 1];
    const float* ew = expw + (size_t)h * N_EDGES;
    float acc = 0.f;
    for (int p = rs; p < re; ++p) {
        const int s = src_s[p];
        acc += ew[p] * xl[(size_t)s * HC + ch];
    }
    const float dn = den[(size_t)h * N_NODES + n];
    float v = acc / (dn + 1e-16f) + bias[ch];
    if (relu) v = fmaxf(v, 0.f);
    out[i] = v;
}

extern "C" void kernel_launch(void* const* d_in, const int* in_sizes, int n_in,
                              void* d_out, int out_size, void* d_ws, size_t ws_size,
                              hipStream_t stream) {
    (void)in_sizes; (void)n_in; (void)out_size; (void)ws_size;
    const float* x     = (const float*)d_in[0];
    const int*   ei    = (const int*)d_in[1];
    const float* eattr = (const float*)d_in[2];
    const int* srcp = ei;
    const int* dstp = ei + N_EDGES;

    // workspace layout
    float* h     = (float*)d_ws;                       // N*80
    float* xl    = h  + (size_t)N_NODES*HC;            // N*80
    float* xr    = xl + (size_t)N_NODES*HC;            // N*80
    float* alpha = xr + (size_t)N_NODES*HC;            // E*5 (logits -> exp in place)
    float* den   = alpha + (size_t)N_EDGES*H_HEADS;    // N*5
    int* rowstart = (int*)(den + (size_t)N_NODES*H_HEADS);   // N+1
    int* cursor   = rowstart + (N_NODES + 1);                // N
    int* perm     = cursor + N_NODES;                        // E
    int* src_s    = perm + N_EDGES;                          // E
    int* dst_s    = src_s + N_EDGES;                         // E
    float* outp  = (float*)d_out;

    const dim3 bx(320);
    const dim3 gx((N_NODES + 63) / 64);
    const dim3 gp(N_EDGES / 64);
    const dim3 geb((N_EDGES + 255) / 256);

    // ---- build CSR by destination (once; graph static across layers) ----
    hipMemsetAsync(cursor, 0, (size_t)N_NODES * sizeof(int), stream);
    k_hist<<<geb, 256, 0, stream>>>(dstp, cursor);
    k_scan<<<1, 1024, 0, stream>>>(cursor, rowstart);
    hipMemsetAsync(cursor, 0, (size_t)N_NODES * sizeof(int), stream);
    k_place<<<geb, 256, 0, stream>>>(srcp, dstp, rowstart, cursor, perm, src_s, dst_s);

    for (int L = 0; L < 3; ++L) {
        const float* in   = (L == 0) ? x : h;
        float*       oacc = (L == 2) ? outp : h;
        const float* wl   = (const float*)d_in[3 + L*7 + 0];
        const float* bl   = (const float*)d_in[3 + L*7 + 1];
        const float* wr   = (const float*)d_in[3 + L*7 + 2];
        const float* br   = (const float*)d_in[3 + L*7 + 3];
        const float* we   = (const float*)d_in[3 + L*7 + 4];
        const float* att  = (const float*)d_in[3 + L*7 + 5];
        const float* bias = (const float*)d_in[3 + L*7 + 6];

        if (L == 0) {
            k_xform<F_IN><<<gx, bx, 0, stream>>>(in, wl, bl, xl, N_NODES);
            k_xform<F_IN><<<gx, bx, 0, stream>>>(in, wr, br, xr, N_NODES);
        } else {
            k_xform<HC><<<gx, bx, 0, stream>>>(in, wl, bl, xl, N_NODES);
            k_xform<HC><<<gx, bx, 0, stream>>>(in, wr, br, xr, N_NODES);
        }
        k_alpha<<<gp, bx, 0, stream>>>(xl, xr, eattr, we, att, perm, src_s, dst_s, alpha);
        k_softmax<<<(N_NODES*H_HEADS + 255)/256, 256, 0, stream>>>(alpha, rowstart, den);
        k_aggregate<<<(N_NODES*HC + 255)/256, 256, 0, stream>>>(
            xl, alpha, den, src_s, rowstart, bias, oacc, (L < 2) ? 1 : 0);
    }
}

// Round 3
// 1488.078 us; speedup vs baseline: 9.7532x; 1.1529x over previous
//
#include <hip/hip_runtime.h>
#include <hip/hip_bf16.h>
#include <math.h>

#define N_NODES 100000
#define N_EDGES 1000000
#define F_IN    128
#define ED_DIM  16
#define H_HEADS 5
#define C_CH    16
#define HC      80
#define NEG_SLOPE 0.2f

#define SCAN_B 256
#define SCAN_G ((N_NODES + SCAN_B - 1) / SCAN_B)   // 391

// ================= CSR build (graph is static across layers) =================

__global__ void k_hist(const int* __restrict__ dst, int* __restrict__ count) {
    const int e = blockIdx.x * 256 + threadIdx.x;
    if (e < N_EDGES) atomicAdd(count + dst[e], 1);
}

// phase 1: per-block partial sums (coalesced)
__global__ __launch_bounds__(SCAN_B) void k_part(const int* __restrict__ count,
                                                 int* __restrict__ partial) {
    const int i = blockIdx.x * SCAN_B + threadIdx.x;
    int v = (i < N_NODES) ? count[i] : 0;
    const int lane = threadIdx.x & 63;
    const int w    = threadIdx.x >> 6;
    __shared__ int ws[SCAN_B / 64];
    #pragma unroll
    for (int o = 32; o > 0; o >>= 1) v += __shfl_down(v, o, 64);
    if (lane == 0) ws[w] = v;
    __syncthreads();
    if (threadIdx.x == 0) {
        int s = 0;
        #pragma unroll
        for (int k = 0; k < SCAN_B / 64; ++k) s += ws[k];
        partial[blockIdx.x] = s;
    }
}

// phase 2: single block scans the 391 partials -> block offsets + rowstart[N]
__global__ __launch_bounds__(512) void k_scanp(const int* __restrict__ partial,
                                               int* __restrict__ blockoff,
                                               int* __restrict__ rowstart) {
    __shared__ int s[512];
    const int t = threadIdx.x;
    int v = (t < SCAN_G) ? partial[t] : 0;
    s[t] = v;
    __syncthreads();
    for (int o = 1; o < 512; o <<= 1) {
        int u = (t >= o) ? s[t - o] : 0;
        __syncthreads();
        s[t] += u;
        __syncthreads();
    }
    if (t < SCAN_G) blockoff[t] = (t == 0) ? 0 : s[t - 1];
    if (t == 0) rowstart[N_NODES] = s[511];
}

// phase 3: in-block exclusive scan + block offset -> rowstart[i]
__global__ __launch_bounds__(SCAN_B) void k_apply(const int* __restrict__ count,
                                                  const int* __restrict__ blockoff,
                                                  int* __restrict__ rowstart) {
    __shared__ int s[SCAN_B];
    const int i = blockIdx.x * SCAN_B + threadIdx.x;
    const int t = threadIdx.x;
    const int v = (i < N_NODES) ? count[i] : 0;
    s[t] = v;
    __syncthreads();
    for (int o = 1; o < SCAN_B; o <<= 1) {
        int u = (t >= o) ? s[t - o] : 0;
        __syncthreads();
        s[t] += u;
        __syncthreads();
    }
    if (i < N_NODES) rowstart[i] = blockoff[blockIdx.x] + (s[t] - v);
}

__global__ void k_place(const int* __restrict__ src, const int* __restrict__ dst,
                        const int* __restrict__ rowstart, int* __restrict__ cursor,
                        int* __restrict__ perm, int* __restrict__ src_s,
                        int* __restrict__ dst_s) {
    const int e = blockIdx.x * 256 + threadIdx.x;
    if (e >= N_EDGES) return;
    const int d = dst[e];
    const int pos = rowstart[d] + atomicAdd(cursor + d, 1);
    perm[pos]  = e;
    src_s[pos] = src[e];
    dst_s[pos] = d;
}

// ====== fused dual node transform: xl = A@WL^T+bL, xr = A@WR^T+bR ============
// tile: 64 nodes x 80 outputs per block, 320 threads, 4x4 micro-tile x2 outputs
template<int DIN>
__global__ __launch_bounds__(320) void k_xform2(
    const float* __restrict__ A,
    const float* __restrict__ WL, const float* __restrict__ bL,
    const float* __restrict__ WR, const float* __restrict__ bR,
    float* __restrict__ outL, float* __restrict__ outR, int nn) {
    __shared__ float As[16][68];
    __shared__ float WsL[16][80];
    __shared__ float WsR[16][80];
    const int t  = threadIdx.x;
    const int n0 = blockIdx.x * 64;
    const int tn = (t & 15) * 4;
    const int tj = (t >> 4) * 4;
    float4 accL[4], accR[4];
    #pragma unroll
    for (int u = 0; u < 4; ++u) {
        accL[u] = make_float4(0.f, 0.f, 0.f, 0.f);
        accR[u] = make_float4(0.f, 0.f, 0.f, 0.f);
    }

    for (int k0 = 0; k0 < DIN; k0 += 16) {
        __syncthreads();
        for (int i = t; i < 64*16; i += 320) {
            int nl = i >> 4, kk = i & 15;
            int n = n0 + nl;
            As[kk][nl] = (n < nn) ? A[(size_t)n*DIN + k0 + kk] : 0.f;
        }
        for (int i = t; i < 80*16; i += 320) {
            int jj = i >> 4, kk = i & 15;
            WsL[kk][jj] = WL[(size_t)jj*DIN + k0 + kk];
            WsR[kk][jj] = WR[(size_t)jj*DIN + k0 + kk];
        }
        __syncthreads();
        #pragma unroll
        for (int k = 0; k < 16; ++k) {
            const float4 av = *(const float4*)&As[k][tn];
            const float4 wl = *(const float4*)&WsL[k][tj];
            const float4 wr = *(const float4*)&WsR[k][tj];
            accL[0].x += av.x*wl.x; accL[0].y += av.x*wl.y; accL[0].z += av.x*wl.z; accL[0].w += av.x*wl.w;
            accL[1].x += av.y*wl.x; accL[1].y += av.y*wl.y; accL[1].z += av.y*wl.z; accL[1].w += av.y*wl.w;
            accL[2].x += av.z*wl.x; accL[2].y += av.z*wl.y; accL[2].z += av.z*wl.z; accL[2].w += av.z*wl.w;
            accL[3].x += av.w*wl.x; accL[3].y += av.w*wl.y; accL[3].z += av.w*wl.z; accL[3].w += av.w*wl.w;
            accR[0].x += av.x*wr.x; accR[0].y += av.x*wr.y; accR[0].z += av.x*wr.z; accR[0].w += av.x*wr.w;
            accR[1].x += av.y*wr.x; accR[1].y += av.y*wr.y; accR[1].z += av.y*wr.z; accR[1].w += av.y*wr.w;
            accR[2].x += av.z*wr.x; accR[2].y += av.z*wr.y; accR[2].z += av.z*wr.z; accR[2].w += av.z*wr.w;
            accR[3].x += av.w*wr.x; accR[3].y += av.w*wr.y; accR[3].z += av.w*wr.z; accR[3].w += av.w*wr.w;
        }
    }
    const float4 bvL = *(const float4*)(bL + tj);
    const float4 bvR = *(const float4*)(bR + tj);
    #pragma unroll
    for (int u = 0; u < 4; ++u) {
        int n = n0 + tn + u;
        if (n < nn) {
            float4 o;
            o.x = accL[u].x + bvL.x; o.y = accL[u].y + bvL.y;
            o.z = accL[u].z + bvL.z; o.w = accL[u].w + bvL.w;
            *(float4*)(outL + (size_t)n*HC + tj) = o;
            o.x = accR[u].x + bvR.x; o.y = accR[u].y + bvR.y;
            o.z = accR[u].z + bvR.z; o.w = accR[u].w + bvR.w;
            *(float4*)(outR + (size_t)n*HC + tj) = o;
        }
    }
}

// ====== alpha logits in SORTED edge order (coalesced write, no atomics) ======
__global__ __launch_bounds__(320) void k_alpha(
    const float* __restrict__ xl, const float* __restrict__ xr,
    const float* __restrict__ eattr, const float* __restrict__ we,
    const float* __restrict__ att, const int* __restrict__ perm,
    const int* __restrict__ src_s, const int* __restrict__ dst_s,
    float* __restrict__ alpha) {
    __shared__ float weS[HC*ED_DIM];
    __shared__ float attS[HC];
    const int t = threadIdx.x;
    for (int i = t; i < HC*ED_DIM; i += 320) weS[i] = we[i];
    if (t < HC) attS[t] = att[t];
    __syncthreads();
    const int h = t >> 6;                       // wave-uniform
    const int p = blockIdx.x * 64 + (t & 63);   // E divisible by 64
    const int e = perm[p];
    const int s = src_s[p];
    const int d = dst_s[p];
    const float4* ea4 = (const float4*)(eattr + (size_t)e * ED_DIM);
    const float4 ea0 = ea4[0], ea1 = ea4[1], ea2 = ea4[2], ea3 = ea4[3];
    const float4* xl4 = (const float4*)(xl + (size_t)s*HC + h*C_CH);
    const float4* xr4 = (const float4*)(xr + (size_t)d*HC + h*C_CH);
    const float4* weH = (const float4*)(weS + h*C_CH*ED_DIM);
    const float4* at4 = (const float4*)(attS + h*C_CH);
    float acc = 0.f;
    #pragma unroll
    for (int cg = 0; cg < 4; ++cg) {
        const float4 xlv = xl4[cg];
        const float4 xrv = xr4[cg];
        const float4 at  = at4[cg];
        float emv[4];
        #pragma unroll
        for (int u = 0; u < 4; ++u) {
            const int c = cg*4 + u;
            const float4 w0 = weH[c*4+0], w1 = weH[c*4+1], w2 = weH[c*4+2], w3 = weH[c*4+3];
            emv[u] = ea0.x*w0.x + ea0.y*w0.y + ea0.z*w0.z + ea0.w*w0.w
                   + ea1.x*w1.x + ea1.y*w1.y + ea1.z*w1.z + ea1.w*w1.w
                   + ea2.x*w2.x + ea2.y*w2.y + ea2.z*w2.z + ea2.w*w2.w
                   + ea3.x*w3.x + ea3.y*w3.y + ea3.z*w3.z + ea3.w*w3.w;
        }
        float4 m;
        m.x = xlv.x + xrv.x + emv[0];
        m.y = xlv.y + xrv.y + emv[1];
        m.z = xlv.z + xrv.z + emv[2];
        m.w = xlv.w + xrv.w + emv[3];
        m.x = fmaxf(m.x, 0.f) + NEG_SLOPE*fminf(m.x, 0.f);
        m.y = fmaxf(m.y, 0.f) + NEG_SLOPE*fminf(m.y, 0.f);
        m.z = fmaxf(m.z, 0.f) + NEG_SLOPE*fminf(m.z, 0.f);
        m.w = fmaxf(m.w, 0.f) + NEG_SLOPE*fminf(m.w, 0.f);
        acc += m.x*at.x + m.y*at.y + m.z*at.z + m.w*at.w;
    }
    alpha[(size_t)h*N_EDGES + p] = acc;   // coalesced
}

// ===== per-(node,head) softmax over CSR segment: exp in place + den ==========
__global__ void k_softmax(float* __restrict__ alpha, const int* __restrict__ rowstart,
                          float* __restrict__ den) {
    const int i = blockIdx.x * 256 + threadIdx.x;
    if (i >= N_NODES * H_HEADS) return;
    const int h = i / N_NODES;
    const int n = i - h * N_NODES;
    const int rs = rowstart[n], re = rowstart[n + 1];
    float* a = alpha + (size_t)h * N_EDGES;
    float mx = -3.402823466e38f;
    for (int p = rs; p < re; ++p) mx = fmaxf(mx, a[p]);
    float s = 0.f;
    for (int p = rs; p < re; ++p) {
        const float ex = __expf(a[p] - mx);
        a[p] = ex;
        s += ex;
    }
    den[(size_t)h * N_NODES + n] = s;
}

// ===== per-(node,channel) aggregation: out = sum(exp*xl[src])/den + bias =====
__global__ void k_aggregate(const float* __restrict__ xl, const float* __restrict__ expw,
                            const float* __restrict__ den, const int* __restrict__ src_s,
                            const int* __restrict__ rowstart, const float* __restrict__ bias,
                            float* __restrict__ out, int relu) {
    const int i = blockIdx.x * 256 + threadIdx.x;
    if (i >= N_NODES * HC) return;
    const int n  = i / HC;
    const int ch = i - n * HC;
    const int h  = ch >> 4;
    const int rs = rowstart[n], re = rowstart[n + 1];
    const float* ew = expw + (size_t)h * N_EDGES;
    float acc = 0.f;
    for (int p = rs; p < re; ++p) {
        const int s = src_s[p];
        acc += ew[p] * xl[(size_t)s * HC + ch];
    }
    const float dn = den[(size_t)h * N_NODES + n];
    float v = acc / (dn + 1e-16f) + bias[ch];
    if (relu) v = fmaxf(v, 0.f);
    out[i] = v;
}

extern "C" void kernel_launch(void* const* d_in, const int* in_sizes, int n_in,
                              void* d_out, int out_size, void* d_ws, size_t ws_size,
                              hipStream_t stream) {
    (void)in_sizes; (void)n_in; (void)out_size; (void)ws_size;
    const float* x     = (const float*)d_in[0];
    const int*   ei    = (const int*)d_in[1];
    const float* eattr = (const float*)d_in[2];
    const int* srcp = ei;
    const int* dstp = ei + N_EDGES;

    // workspace layout
    float* h     = (float*)d_ws;                       // N*80
    float* xl    = h  + (size_t)N_NODES*HC;            // N*80
    float* xr    = xl + (size_t)N_NODES*HC;            // N*80
    float* alpha = xr + (size_t)N_NODES*HC;            // E*5 (logits -> exp in place)
    float* den   = alpha + (size_t)N_EDGES*H_HEADS;    // N*5
    int* rowstart = (int*)(den + (size_t)N_NODES*H_HEADS);   // N+1
    int* cursor   = rowstart + (N_NODES + 1);                // N
    int* perm     = cursor + N_NODES;                        // E
    int* src_s    = perm + N_EDGES;                          // E
    int* dst_s    = src_s + N_EDGES;                         // E
    int* partial  = dst_s + N_EDGES;                         // SCAN_G
    int* blockoff = partial + SCAN_G;                        // SCAN_G
    float* outp  = (float*)d_out;

    const dim3 bx(320);
    const dim3 gx((N_NODES + 63) / 64);
    const dim3 gp(N_EDGES / 64);
    const dim3 geb((N_EDGES + 255) / 256);

    // ---- build CSR by destination (once; graph static across layers) ----
    hipMemsetAsync(cursor, 0, (size_t)N_NODES * sizeof(int), stream);
    k_hist<<<geb, 256, 0, stream>>>(dstp, cursor);
    k_part<<<SCAN_G, SCAN_B, 0, stream>>>(cursor, partial);
    k_scanp<<<1, 512, 0, stream>>>(partial, blockoff, rowstart);
    k_apply<<<SCAN_G, SCAN_B, 0, stream>>>(cursor, blockoff, rowstart);
    hipMemsetAsync(cursor, 0, (size_t)N_NODES * sizeof(int), stream);
    k_place<<<geb, 256, 0, stream>>>(srcp, dstp, rowstart, cursor, perm, src_s, dst_s);

    for (int L = 0; L < 3; ++L) {
        const float* in   = (L == 0) ? x : h;
        float*       oacc = (L == 2) ? outp : h;
        const float* wl   = (const float*)d_in[3 + L*7 + 0];
        const float* bl   = (const float*)d_in[3 + L*7 + 1];
        const float* wr   = (const float*)d_in[3 + L*7 + 2];
        const float* br   = (const float*)d_in[3 + L*7 + 3];
        const float* we   = (const float*)d_in[3 + L*7 + 4];
        const float* att  = (const float*)d_in[3 + L*7 + 5];
        const float* bias = (const float*)d_in[3 + L*7 + 6];

        if (L == 0) {
            k_xform2<F_IN><<<gx, bx, 0, stream>>>(in, wl, bl, wr, br, xl, xr, N_NODES);
        } else {
            k_xform2<HC><<<gx, bx, 0, stream>>>(in, wl, bl, wr, br, xl, xr, N_NODES);
        }
        k_alpha<<<gp, bx, 0, stream>>>(xl, xr, eattr, we, att, perm, src_s, dst_s, alpha);
        k_softmax<<<(N_NODES*H_HEADS + 255)/256, 256, 0, stream>>>(alpha, rowstart, den);
        k_aggregate<<<(N_NODES*HC + 255)/256, 256, 0, stream>>>(
            xl, alpha, den, src_s, rowstart, bias, oacc, (L < 2) ? 1 : 0);
    }
}